// Round 9
// baseline (468.597 us; speedup 1.0000x reference)
//
#include <hip/hip_runtime.h>
#include <stdint.h>

// Problem constants
#define BB 4
#define TT 2048
#define EE 1024
#define HH 16
#define DD 64
#define MM (BB*TT)        // 8192
#define NQKV (3*EE)       // 3072

typedef __bf16 bf16_t;
typedef bf16_t bf16x8 __attribute__((ext_vector_type(8)));
typedef short  s16x4  __attribute__((ext_vector_type(4)));
typedef float  floatx4 __attribute__((ext_vector_type(4)));

__device__ __forceinline__ unsigned short f2bf(float f) {
    unsigned int u = __float_as_uint(f);
    u = (u + 0x7FFFu + ((u >> 16) & 1u)) >> 16;
    return (unsigned short)u;
}

// compiler-mediated f32->bf16 (RNE); backend pairs into v_cvt_pk_bf16_f32 itself.
__device__ __forceinline__ short bfs(float f) {
    return (short)__builtin_bit_cast(unsigned short, (bf16_t)f);
}

__device__ __forceinline__ void load_lds16(const void* g, void* l) {
    __builtin_amdgcn_global_load_lds(
        (const __attribute__((address_space(1))) unsigned int*)g,
        (__attribute__((address_space(3))) unsigned int*)l, 16, 0, 0);
}

// ---------------------------------------------------------------- convert
__global__ void cvt_f32_bf16(const float* __restrict__ in,
                             unsigned short* __restrict__ out, int n) {
    int i = (blockIdx.x * 256 + threadIdx.x) * 4;
    if (i + 3 < n) {
        float4 v = *reinterpret_cast<const float4*>(in + i);
        ushort4 o;
        o.x = f2bf(v.x); o.y = f2bf(v.y); o.z = f2bf(v.z); o.w = f2bf(v.w);
        *reinterpret_cast<ushort4*>(out + i) = o;
    }
}

// ---------------------------------------------------------------- GEMM v5 (B^T input)
// R0's proven structure + chunk-XOR LDS swizzle (R8: SQ_LDS_BANK_CONFLICT 6.29M -> 0,
// time neutral -> conflicts were hidden by 3-block/CU overlap; kept because free).
// Ledger: R5 full conflict fix via row-scatter = +40us (TA merge loss). R1/R2/R4
// hand-scheduled 1-block/CU 256-tiles = 118-133us. This structure = 89.5us, the
// local optimum for the GEMMs.
template<int N, int K, int EPI>
__global__ __launch_bounds__(256, 3) void gemm_bt(
    const unsigned short* __restrict__ A,
    const unsigned short* __restrict__ Bw,
    const float* __restrict__ bias,
    const float* __restrict__ sscale,
    unsigned short* __restrict__ Qb,
    unsigned short* __restrict__ Kb,
    unsigned short* __restrict__ Vtb,
    float* __restrict__ Cout)
{
    __shared__ __align__(16) unsigned short As[2][128 * 32];   // [k-half][row][32]
    __shared__ __align__(16) unsigned short Bs[2][128 * 32];
    __shared__ float qsc[16];

    const int tid  = threadIdx.x;
    const int lane = tid & 63;
    const int w    = tid >> 6;
    const int quad = lane >> 4;
    const int l16  = lane & 15;
    const int m0   = blockIdx.y * 128;
    const int n0   = blockIdx.x * 128;
    const int wm   = (w & 1) * 64;
    const int wn   = (w >> 1) * 64;

    if (EPI == 0 && tid < 16) qsc[tid] = (1.0f + 0.01f * tanhf(sscale[tid])) * 0.125f;

    floatx4 acc[4][4] = {};

    // read-side swizzled chunk slot (ushort offset): quad ^ ((l16>>1)&3)
    const int rsl = (quad ^ ((l16 >> 1) & 3)) * 8;

    for (int kk = 0; kk < K; kk += 64) {
        __syncthreads();   // WAR: previous pair's fragment reads done
#pragma unroll
        for (int h = 0; h < 2; ++h) {
#pragma unroll
            for (int c = 0; c < 2; ++c) {
                int idx = c * 256 + tid;
                int chk = (idx & 3) ^ ((idx >> 3) & 3);   // chunk-XOR within 64B group
                const unsigned short* ga = A  + (size_t)(m0 + (idx >> 2)) * K + kk + h * 32 + chk * 8;
                load_lds16(ga, &As[h][(c * 256 + w * 64) * 8]);
                const unsigned short* gb = Bw + (size_t)(n0 + (idx >> 2)) * K + kk + h * 32 + chk * 8;
                load_lds16(gb, &Bs[h][(c * 256 + w * 64) * 8]);
            }
        }
        __syncthreads();   // data ready (compiler emits the vmcnt(0) drain here)

#pragma unroll
        for (int h = 0; h < 2; ++h) {
            bf16x8 af[4], bfr[4];
#pragma unroll
            for (int mt = 0; mt < 4; ++mt)
                af[mt] = *reinterpret_cast<const bf16x8*>(&As[h][(wm + mt * 16 + l16) * 32 + rsl]);
#pragma unroll
            for (int nt = 0; nt < 4; ++nt)
                bfr[nt] = *reinterpret_cast<const bf16x8*>(&Bs[h][(wn + nt * 16 + l16) * 32 + rsl]);
#pragma unroll
            for (int mt = 0; mt < 4; ++mt)
#pragma unroll
                for (int nt = 0; nt < 4; ++nt)
                    acc[mt][nt] = __builtin_amdgcn_mfma_f32_16x16x32_bf16(af[mt], bfr[nt], acc[mt][nt], 0, 0, 0);
        }
    }

    if (EPI == 0) {
#pragma unroll
        for (int mt = 0; mt < 4; ++mt) {
            int rowb = m0 + wm + mt * 16 + quad * 4;
#pragma unroll
            for (int nt = 0; nt < 4; ++nt) {
                int col = n0 + wn + nt * 16 + l16;   // 0..3071
                int which = col >> 10;               // 0=q 1=k 2=v
                int e = col & 1023;
                int h = e >> 6, d = e & 63;
                float bsv = bias[col];
#pragma unroll
                for (int r = 0; r < 4; ++r) {
                    int m = rowb + r;                // b*T + t
                    int b = m >> 11, t = m & 2047;
                    float v = acc[mt][nt][r] + bsv;
                    size_t bh = (size_t)(b * HH + h);
                    if (which == 0) {
                        v *= qsc[h];
                        Qb[(bh * TT + t) * DD + d] = f2bf(v);
                    } else if (which == 1) {
                        Kb[(bh * TT + t) * DD + d] = f2bf(v);
                    } else {
                        Vtb[(bh * DD + d) * TT + t] = f2bf(v);
                    }
                }
            }
        }
    } else {
#pragma unroll
        for (int mt = 0; mt < 4; ++mt) {
            int rowb = m0 + wm + mt * 16 + quad * 4;
#pragma unroll
            for (int nt = 0; nt < 4; ++nt) {
                int col = n0 + wn + nt * 16 + l16;
                float bsv = bias[col];
#pragma unroll
                for (int r = 0; r < 4; ++r)
                    Cout[(size_t)(rowb + r) * N + col] = acc[mt][nt][r] + bsv;
            }
        }
    }
}

// ---------------------------------------------------------------- flash attention v9
// v9: 128 q-rows per block (wave owns TWO 16-row groups, +64 apart), grid 1024.
// Rationale: static model says v8 was LDS-throughput-bound (~80KB LDS moved per
// block-tile ~ 965 cyc vs ~550 MFMA cyc). K-frags and V-frags are now read ONCE per
// tile and fed to both q-groups -> LDS read+stage traffic and K/V global re-fetch
// per unit work HALVED. Compute identical: group0 runs kt in [0,2qb] (diag 2qb,
// wave-uniform skip at 2qb+1), group1 runs kt in [0,2qb+1] (diag 2qb+1); total
// 4qb+3 MFMA-tiles = exactly the two old 64-row blocks this replaces.
#define LP 72   // padded LDS row stride: 144B -> dword stride 36
__global__ __launch_bounds__(256, 4) void flash_attn(
    const unsigned short* __restrict__ Qb,
    const unsigned short* __restrict__ Kb,
    const unsigned short* __restrict__ Vtb,
    unsigned short* __restrict__ Ob)
{
    __shared__ __align__(16) unsigned short Ks[2][64 * LP];   // [buf][key][d]
    __shared__ __align__(16) unsigned short Vs[2][64 * LP];   // [buf][d][key]

    const int tid  = threadIdx.x;
    const int lane = tid & 63;
    const int w    = tid >> 6;
    const int quad = lane >> 4;
    const int l16  = lane & 15;
    const int i    = blockIdx.x;
    const int bh   = i & 63;               // 0..63
    const int qb   = 15 - (i >> 6);        // 0..15, heavy first; 128 q-rows per block
    const int row0 = qb * 128 + w * 16;    // group0 rows; group1 = row0 + 64

    // Q fragments for both groups (B-operand: n=qrow, k=d)
    const unsigned short* qbase = &Qb[((size_t)bh * TT + row0 + l16) * DD + quad * 8];
    const bf16x8 qf0 = *reinterpret_cast<const bf16x8*>(qbase);
    const bf16x8 qf1 = *reinterpret_cast<const bf16x8*>(qbase + 32);
    const bf16x8 qg0 = *reinterpret_cast<const bf16x8*>(qbase + 64 * DD);
    const bf16x8 qg1 = *reinterpret_cast<const bf16x8*>(qbase + 64 * DD + 32);

    const s16x4 vones = { (short)0x3F80, (short)0x3F80, (short)0x3F80, (short)0x3F80 };

    floatx4 o[4] = {}, ob[4] = {};
    floatx4 o1 = {}, o1b = {};   // row sums per group

    const int srow = tid >> 3;            // 0..31
    const int scol = (tid & 7) * 8;       // 0..56
    const size_t kgbase = ((size_t)bh * TT + srow) * DD + scol;
    const size_t vgbase = ((size_t)bh * DD + srow) * TT + scol;

    uint4 kr0 = *reinterpret_cast<const uint4*>(&Kb[kgbase]);
    uint4 kr1 = *reinterpret_cast<const uint4*>(&Kb[kgbase + 32 * DD]);
    uint4 vr0 = *reinterpret_cast<const uint4*>(&Vtb[vgbase]);
    uint4 vr1 = *reinterpret_cast<const uint4*>(&Vtb[vgbase + 32 * TT]);

    const int ktmax = 2 * qb + 1;

    for (int kt = 0; kt <= ktmax; ++kt) {
        const int buf = kt & 1;
        *reinterpret_cast<uint4*>(&Ks[buf][srow * LP + scol]) = kr0;
        *reinterpret_cast<uint4*>(&Ks[buf][(srow + 32) * LP + scol]) = kr1;
        *reinterpret_cast<uint4*>(&Vs[buf][srow * LP + scol]) = vr0;
        *reinterpret_cast<uint4*>(&Vs[buf][(srow + 32) * LP + scol]) = vr1;
        __syncthreads();

        if (kt < ktmax) {
            size_t ko = kgbase + (size_t)(kt + 1) * 64 * DD;
            size_t vo = vgbase + (size_t)(kt + 1) * 64;
            kr0 = *reinterpret_cast<const uint4*>(&Kb[ko]);
            kr1 = *reinterpret_cast<const uint4*>(&Kb[ko + 32 * DD]);
            vr0 = *reinterpret_cast<const uint4*>(&Vtb[vo]);
            vr1 = *reinterpret_cast<const uint4*>(&Vtb[vo + 32 * TT]);
        }

        const int keyb  = kt * 64 + quad * 4;
        const int qr0   = row0 + l16;          // group0 q-row; group1 = qr0 + 64
        const bool g0on = (kt <= 2 * qb);      // group0 fully masked at kt = 2qb+1
        const bool g0di = (kt == 2 * qb);
        const bool g1di = (kt == ktmax);

#pragma unroll
        for (int ntk = 0; ntk < 4; ++ntk) {
            const unsigned short* krow = &Ks[buf][(ntk * 16 + l16) * LP + quad * 8];
            bf16x8 kf0 = *reinterpret_cast<const bf16x8*>(krow);
            bf16x8 kf1 = *reinterpret_cast<const bf16x8*>(krow + 32);

            s16x4 pf, pfb;
            if (g0on) {                        // ---- group 0 scores
                floatx4 st = {0.f, 0.f, 0.f, 0.f};
                st = __builtin_amdgcn_mfma_f32_16x16x32_bf16(kf0, qf0, st, 0, 0, 0);
                st = __builtin_amdgcn_mfma_f32_16x16x32_bf16(kf1, qf1, st, 0, 0, 0);
                float p0 = __expf(st[0]), p1 = __expf(st[1]);
                float p2 = __expf(st[2]), p3 = __expf(st[3]);
                if (g0di) {
                    const int kb = keyb + ntk * 16;
                    p0 = (kb + 0 <= qr0) ? p0 : 0.f;
                    p1 = (kb + 1 <= qr0) ? p1 : 0.f;
                    p2 = (kb + 2 <= qr0) ? p2 : 0.f;
                    p3 = (kb + 3 <= qr0) ? p3 : 0.f;
                }
                pf[0] = bfs(p0); pf[1] = bfs(p1); pf[2] = bfs(p2); pf[3] = bfs(p3);
                o1 = __builtin_amdgcn_mfma_f32_16x16x16bf16_1k(pf, vones, o1, 0, 0, 0);
            }
            {                                  // ---- group 1 scores
                floatx4 st = {0.f, 0.f, 0.f, 0.f};
                st = __builtin_amdgcn_mfma_f32_16x16x32_bf16(kf0, qg0, st, 0, 0, 0);
                st = __builtin_amdgcn_mfma_f32_16x16x32_bf16(kf1, qg1, st, 0, 0, 0);
                float p0 = __expf(st[0]), p1 = __expf(st[1]);
                float p2 = __expf(st[2]), p3 = __expf(st[3]);
                if (g1di) {
                    const int kb = keyb + ntk * 16, qr1 = qr0 + 64;
                    p0 = (kb + 0 <= qr1) ? p0 : 0.f;
                    p1 = (kb + 1 <= qr1) ? p1 : 0.f;
                    p2 = (kb + 2 <= qr1) ? p2 : 0.f;
                    p3 = (kb + 3 <= qr1) ? p3 : 0.f;
                }
                pfb[0] = bfs(p0); pfb[1] = bfs(p1); pfb[2] = bfs(p2); pfb[3] = bfs(p3);
                o1b = __builtin_amdgcn_mfma_f32_16x16x16bf16_1k(pfb, vones, o1b, 0, 0, 0);
            }
            // ---- shared V reads feed both groups' PV
#pragma unroll
            for (int dt = 0; dt < 4; ++dt) {
                s16x4 vf = *reinterpret_cast<const s16x4*>(
                    &Vs[buf][(dt * 16 + l16) * LP + ntk * 16 + quad * 4]);
                if (g0on) o[dt] = __builtin_amdgcn_mfma_f32_16x16x16bf16_1k(pf, vf, o[dt], 0, 0, 0);
                ob[dt] = __builtin_amdgcn_mfma_f32_16x16x16bf16_1k(pfb, vf, ob[dt], 0, 0, 0);
            }
        }
    }

    // epilogue: ctx[b, q, h*64+d] bf16  (C-layout: qrow=quad*4+r, d=l16)
    const int b = bh >> 4, h = bh & 15;
#pragma unroll
    for (int r = 0; r < 4; ++r) {
        int q0 = row0 + quad * 4 + r;
        float rl0 = __builtin_amdgcn_rcpf(o1[r]);
        float rl1 = __builtin_amdgcn_rcpf(o1b[r]);
#pragma unroll
        for (int dt = 0; dt < 4; ++dt) {
            Ob[((size_t)(b * TT + q0)) * EE + h * DD + dt * 16 + l16] =
                f2bf(o[dt][r] * rl0);
            Ob[((size_t)(b * TT + q0 + 64)) * EE + h * DD + dt * 16 + l16] =
                f2bf(ob[dt][r] * rl1);
        }
    }
}

// ---------------------------------------------------------------- launch
extern "C" void kernel_launch(void* const* d_in, const int* in_sizes, int n_in,
                              void* d_out, int out_size, void* d_ws, size_t ws_size,
                              hipStream_t stream) {
    const float* hs    = (const float*)d_in[0];
    const float* Wqkv  = (const float*)d_in[1];
    const float* bqkv  = (const float*)d_in[2];
    const float* Wproj = (const float*)d_in[3];
    const float* bproj = (const float*)d_in[4];
    const float* ss    = (const float*)d_in[5];
    // d_in[6] = splat_bias: softmax-invariant (uniform shift of unmasked logits), unused
    float* out = (float*)d_out;

    char* p = (char*)d_ws;
    unsigned short* hsb    = (unsigned short*)p; p += (size_t)MM * EE * 2;      // 16.8 MB (reused as ctx)
    unsigned short* wqkvb  = (unsigned short*)p; p += (size_t)NQKV * EE * 2;    //  6.3 MB
    unsigned short* wprojb = (unsigned short*)p; p += (size_t)EE * EE * 2;      //  2.1 MB
    unsigned short* Qb     = (unsigned short*)p; p += (size_t)BB*HH*TT*DD * 2;  // 16.8 MB
    unsigned short* Kb     = (unsigned short*)p; p += (size_t)BB*HH*TT*DD * 2;  // 16.8 MB
    unsigned short* Vtb    = (unsigned short*)p; p += (size_t)BB*HH*TT*DD * 2;  // 16.8 MB

    cvt_f32_bf16<<<(MM * EE) / 1024, 256, 0, stream>>>(hs, hsb, MM * EE);
    cvt_f32_bf16<<<(NQKV * EE) / 1024, 256, 0, stream>>>(Wqkv, wqkvb, NQKV * EE);
    cvt_f32_bf16<<<(EE * EE) / 1024, 256, 0, stream>>>(Wproj, wprojb, EE * EE);

    gemm_bt<NQKV, EE, 0><<<dim3(NQKV / 128, MM / 128), 256, 0, stream>>>(
        hsb, wqkvb, bqkv, ss, Qb, Kb, Vtb, nullptr);

    flash_attn<<<dim3(1024), 256, 0, stream>>>(Qb, Kb, Vtb, hsb);

    gemm_bt<EE, EE, 1><<<dim3(EE / 128, MM / 128), 256, 0, stream>>>(
        hsb, wprojb, bproj, nullptr, nullptr, nullptr, nullptr, out);
}

// Round 10
// 290.279 us; speedup vs baseline: 1.6143x; 1.6143x over previous
//
#include <hip/hip_runtime.h>
#include <stdint.h>

// Problem constants
#define BB 4
#define TT 2048
#define EE 1024
#define HH 16
#define DD 64
#define MM (BB*TT)        // 8192
#define NQKV (3*EE)       // 3072

typedef __bf16 bf16_t;
typedef bf16_t bf16x8 __attribute__((ext_vector_type(8)));
typedef short  s16x4  __attribute__((ext_vector_type(4)));
typedef float  floatx4 __attribute__((ext_vector_type(4)));

__device__ __forceinline__ unsigned short f2bf(float f) {
    unsigned int u = __float_as_uint(f);
    u = (u + 0x7FFFu + ((u >> 16) & 1u)) >> 16;
    return (unsigned short)u;
}

// compiler-mediated f32->bf16 (RNE); backend pairs into v_cvt_pk_bf16_f32 itself.
__device__ __forceinline__ short bfs(float f) {
    return (short)__builtin_bit_cast(unsigned short, (bf16_t)f);
}

__device__ __forceinline__ void load_lds16(const void* g, void* l) {
    __builtin_amdgcn_global_load_lds(
        (const __attribute__((address_space(1))) unsigned int*)g,
        (__attribute__((address_space(3))) unsigned int*)l, 16, 0, 0);
}

// ---------------------------------------------------------------- convert
__global__ void cvt_f32_bf16(const float* __restrict__ in,
                             unsigned short* __restrict__ out, int n) {
    int i = (blockIdx.x * 256 + threadIdx.x) * 4;
    if (i + 3 < n) {
        float4 v = *reinterpret_cast<const float4*>(in + i);
        ushort4 o;
        o.x = f2bf(v.x); o.y = f2bf(v.y); o.z = f2bf(v.z); o.w = f2bf(v.w);
        *reinterpret_cast<ushort4*>(out + i) = o;
    }
}

// ---------------------------------------------------------------- GEMM v5 (B^T input)
// R0's proven structure + chunk-XOR LDS swizzle (R8: SQ_LDS_BANK_CONFLICT 6.29M -> 0,
// time neutral -> conflicts were hidden by 3-block/CU overlap; kept because free).
// Ledger: R5 full conflict fix via row-scatter = +40us (TA merge loss). R1/R2/R4
// hand-scheduled 1-block/CU 256-tiles = 118-133us. This structure = 89.5us, the
// local optimum for the GEMMs.
template<int N, int K, int EPI>
__global__ __launch_bounds__(256, 3) void gemm_bt(
    const unsigned short* __restrict__ A,
    const unsigned short* __restrict__ Bw,
    const float* __restrict__ bias,
    const float* __restrict__ sscale,
    unsigned short* __restrict__ Qb,
    unsigned short* __restrict__ Kb,
    unsigned short* __restrict__ Vtb,
    float* __restrict__ Cout)
{
    __shared__ __align__(16) unsigned short As[2][128 * 32];   // [k-half][row][32]
    __shared__ __align__(16) unsigned short Bs[2][128 * 32];
    __shared__ float qsc[16];

    const int tid  = threadIdx.x;
    const int lane = tid & 63;
    const int w    = tid >> 6;
    const int quad = lane >> 4;
    const int l16  = lane & 15;
    const int m0   = blockIdx.y * 128;
    const int n0   = blockIdx.x * 128;
    const int wm   = (w & 1) * 64;
    const int wn   = (w >> 1) * 64;

    if (EPI == 0 && tid < 16) qsc[tid] = (1.0f + 0.01f * tanhf(sscale[tid])) * 0.125f;

    floatx4 acc[4][4] = {};

    // read-side swizzled chunk slot (ushort offset): quad ^ ((l16>>1)&3)
    const int rsl = (quad ^ ((l16 >> 1) & 3)) * 8;

    for (int kk = 0; kk < K; kk += 64) {
        __syncthreads();   // WAR: previous pair's fragment reads done
#pragma unroll
        for (int h = 0; h < 2; ++h) {
#pragma unroll
            for (int c = 0; c < 2; ++c) {
                int idx = c * 256 + tid;
                int chk = (idx & 3) ^ ((idx >> 3) & 3);   // chunk-XOR within 64B group
                const unsigned short* ga = A  + (size_t)(m0 + (idx >> 2)) * K + kk + h * 32 + chk * 8;
                load_lds16(ga, &As[h][(c * 256 + w * 64) * 8]);
                const unsigned short* gb = Bw + (size_t)(n0 + (idx >> 2)) * K + kk + h * 32 + chk * 8;
                load_lds16(gb, &Bs[h][(c * 256 + w * 64) * 8]);
            }
        }
        __syncthreads();   // data ready (compiler emits the vmcnt(0) drain here)

#pragma unroll
        for (int h = 0; h < 2; ++h) {
            bf16x8 af[4], bfr[4];
#pragma unroll
            for (int mt = 0; mt < 4; ++mt)
                af[mt] = *reinterpret_cast<const bf16x8*>(&As[h][(wm + mt * 16 + l16) * 32 + rsl]);
#pragma unroll
            for (int nt = 0; nt < 4; ++nt)
                bfr[nt] = *reinterpret_cast<const bf16x8*>(&Bs[h][(wn + nt * 16 + l16) * 32 + rsl]);
#pragma unroll
            for (int mt = 0; mt < 4; ++mt)
#pragma unroll
                for (int nt = 0; nt < 4; ++nt)
                    acc[mt][nt] = __builtin_amdgcn_mfma_f32_16x16x32_bf16(af[mt], bfr[nt], acc[mt][nt], 0, 0, 0);
        }
    }

    if (EPI == 0) {
#pragma unroll
        for (int mt = 0; mt < 4; ++mt) {
            int rowb = m0 + wm + mt * 16 + quad * 4;
#pragma unroll
            for (int nt = 0; nt < 4; ++nt) {
                int col = n0 + wn + nt * 16 + l16;   // 0..3071
                int which = col >> 10;               // 0=q 1=k 2=v
                int e = col & 1023;
                int h = e >> 6, d = e & 63;
                float bsv = bias[col];
#pragma unroll
                for (int r = 0; r < 4; ++r) {
                    int m = rowb + r;                // b*T + t
                    int b = m >> 11, t = m & 2047;
                    float v = acc[mt][nt][r] + bsv;
                    size_t bh = (size_t)(b * HH + h);
                    if (which == 0) {
                        v *= qsc[h];
                        Qb[(bh * TT + t) * DD + d] = f2bf(v);
                    } else if (which == 1) {
                        Kb[(bh * TT + t) * DD + d] = f2bf(v);
                    } else {
                        Vtb[(bh * DD + d) * TT + t] = f2bf(v);
                    }
                }
            }
        }
    } else {
#pragma unroll
        for (int mt = 0; mt < 4; ++mt) {
            int rowb = m0 + wm + mt * 16 + quad * 4;
#pragma unroll
            for (int nt = 0; nt < 4; ++nt) {
                int col = n0 + wn + nt * 16 + l16;
                float bsv = bias[col];
#pragma unroll
                for (int r = 0; r < 4; ++r)
                    Cout[(size_t)(rowb + r) * N + col] = acc[mt][nt][r] + bsv;
            }
        }
    }
}

// ---------------------------------------------------------------- flash attention v10
// v10 = v9 (128 q-rows/block, K/V frags shared by two q-groups, grid 1024) with the
// R9 spill fixed. R9 diagnosis: launch_bounds(256,4) capped VGPRs at 128 < true
// pressure (~130-160) -> accumulator spill -> FETCH+WRITE 620MB of scratch traffic,
// MfmaUtil 9%, 280us. v10: launch_bounds(256,3) -> 168-VGPR budget, no spill,
// 3 blocks/CU (12 waves/CU). Reuse math unchanged: K-frag reads, stage traffic and
// K/V global refetch per unit work are HALF of v8's. Compute identical to v8
// (group0 kt in [0,2qb], group1 kt in [0,2qb+1]; total 4qb+3 MFMA-tiles = the two
// 64-row blocks this replaces).
#define LP 72   // padded LDS row stride: 144B -> dword stride 36
__global__ __launch_bounds__(256, 3) void flash_attn(
    const unsigned short* __restrict__ Qb,
    const unsigned short* __restrict__ Kb,
    const unsigned short* __restrict__ Vtb,
    unsigned short* __restrict__ Ob)
{
    __shared__ __align__(16) unsigned short Ks[2][64 * LP];   // [buf][key][d]
    __shared__ __align__(16) unsigned short Vs[2][64 * LP];   // [buf][d][key]

    const int tid  = threadIdx.x;
    const int lane = tid & 63;
    const int w    = tid >> 6;
    const int quad = lane >> 4;
    const int l16  = lane & 15;
    const int i    = blockIdx.x;
    const int bh   = i & 63;               // 0..63
    const int qb   = 15 - (i >> 6);        // 0..15, heavy first; 128 q-rows per block
    const int row0 = qb * 128 + w * 16;    // group0 rows; group1 = row0 + 64

    // Q fragments for both groups (B-operand: n=qrow, k=d)
    const unsigned short* qbase = &Qb[((size_t)bh * TT + row0 + l16) * DD + quad * 8];
    const bf16x8 qf0 = *reinterpret_cast<const bf16x8*>(qbase);
    const bf16x8 qf1 = *reinterpret_cast<const bf16x8*>(qbase + 32);
    const bf16x8 qg0 = *reinterpret_cast<const bf16x8*>(qbase + 64 * DD);
    const bf16x8 qg1 = *reinterpret_cast<const bf16x8*>(qbase + 64 * DD + 32);

    const s16x4 vones = { (short)0x3F80, (short)0x3F80, (short)0x3F80, (short)0x3F80 };

    floatx4 o[4] = {}, ob[4] = {};
    floatx4 o1 = {}, o1b = {};   // row sums per group

    const int srow = tid >> 3;            // 0..31
    const int scol = (tid & 7) * 8;       // 0..56
    const size_t kgbase = ((size_t)bh * TT + srow) * DD + scol;
    const size_t vgbase = ((size_t)bh * DD + srow) * TT + scol;

    uint4 kr0 = *reinterpret_cast<const uint4*>(&Kb[kgbase]);
    uint4 kr1 = *reinterpret_cast<const uint4*>(&Kb[kgbase + 32 * DD]);
    uint4 vr0 = *reinterpret_cast<const uint4*>(&Vtb[vgbase]);
    uint4 vr1 = *reinterpret_cast<const uint4*>(&Vtb[vgbase + 32 * TT]);

    const int ktmax = 2 * qb + 1;

    for (int kt = 0; kt <= ktmax; ++kt) {
        const int buf = kt & 1;
        *reinterpret_cast<uint4*>(&Ks[buf][srow * LP + scol]) = kr0;
        *reinterpret_cast<uint4*>(&Ks[buf][(srow + 32) * LP + scol]) = kr1;
        *reinterpret_cast<uint4*>(&Vs[buf][srow * LP + scol]) = vr0;
        *reinterpret_cast<uint4*>(&Vs[buf][(srow + 32) * LP + scol]) = vr1;
        __syncthreads();

        if (kt < ktmax) {
            size_t ko = kgbase + (size_t)(kt + 1) * 64 * DD;
            size_t vo = vgbase + (size_t)(kt + 1) * 64;
            kr0 = *reinterpret_cast<const uint4*>(&Kb[ko]);
            kr1 = *reinterpret_cast<const uint4*>(&Kb[ko + 32 * DD]);
            vr0 = *reinterpret_cast<const uint4*>(&Vtb[vo]);
            vr1 = *reinterpret_cast<const uint4*>(&Vtb[vo + 32 * TT]);
        }

        const int keyb  = kt * 64 + quad * 4;
        const int qr0   = row0 + l16;          // group0 q-row; group1 = qr0 + 64
        const bool g0on = (kt <= 2 * qb);      // group0 fully masked at kt = 2qb+1
        const bool g0di = (kt == 2 * qb);
        const bool g1di = (kt == ktmax);

#pragma unroll
        for (int ntk = 0; ntk < 4; ++ntk) {
            const unsigned short* krow = &Ks[buf][(ntk * 16 + l16) * LP + quad * 8];
            bf16x8 kf0 = *reinterpret_cast<const bf16x8*>(krow);
            bf16x8 kf1 = *reinterpret_cast<const bf16x8*>(krow + 32);

            s16x4 pf, pfb;
            if (g0on) {                        // ---- group 0 scores
                floatx4 st = {0.f, 0.f, 0.f, 0.f};
                st = __builtin_amdgcn_mfma_f32_16x16x32_bf16(kf0, qf0, st, 0, 0, 0);
                st = __builtin_amdgcn_mfma_f32_16x16x32_bf16(kf1, qf1, st, 0, 0, 0);
                float p0 = __expf(st[0]), p1 = __expf(st[1]);
                float p2 = __expf(st[2]), p3 = __expf(st[3]);
                if (g0di) {
                    const int kb = keyb + ntk * 16;
                    p0 = (kb + 0 <= qr0) ? p0 : 0.f;
                    p1 = (kb + 1 <= qr0) ? p1 : 0.f;
                    p2 = (kb + 2 <= qr0) ? p2 : 0.f;
                    p3 = (kb + 3 <= qr0) ? p3 : 0.f;
                }
                pf[0] = bfs(p0); pf[1] = bfs(p1); pf[2] = bfs(p2); pf[3] = bfs(p3);
                o1 = __builtin_amdgcn_mfma_f32_16x16x16bf16_1k(pf, vones, o1, 0, 0, 0);
            }
            {                                  // ---- group 1 scores
                floatx4 st = {0.f, 0.f, 0.f, 0.f};
                st = __builtin_amdgcn_mfma_f32_16x16x32_bf16(kf0, qg0, st, 0, 0, 0);
                st = __builtin_amdgcn_mfma_f32_16x16x32_bf16(kf1, qg1, st, 0, 0, 0);
                float p0 = __expf(st[0]), p1 = __expf(st[1]);
                float p2 = __expf(st[2]), p3 = __expf(st[3]);
                if (g1di) {
                    const int kb = keyb + ntk * 16, qr1 = qr0 + 64;
                    p0 = (kb + 0 <= qr1) ? p0 : 0.f;
                    p1 = (kb + 1 <= qr1) ? p1 : 0.f;
                    p2 = (kb + 2 <= qr1) ? p2 : 0.f;
                    p3 = (kb + 3 <= qr1) ? p3 : 0.f;
                }
                pfb[0] = bfs(p0); pfb[1] = bfs(p1); pfb[2] = bfs(p2); pfb[3] = bfs(p3);
                o1b = __builtin_amdgcn_mfma_f32_16x16x16bf16_1k(pfb, vones, o1b, 0, 0, 0);
            }
            // ---- shared V reads feed both groups' PV
#pragma unroll
            for (int dt = 0; dt < 4; ++dt) {
                s16x4 vf = *reinterpret_cast<const s16x4*>(
                    &Vs[buf][(dt * 16 + l16) * LP + ntk * 16 + quad * 4]);
                if (g0on) o[dt] = __builtin_amdgcn_mfma_f32_16x16x16bf16_1k(pf, vf, o[dt], 0, 0, 0);
                ob[dt] = __builtin_amdgcn_mfma_f32_16x16x16bf16_1k(pfb, vf, ob[dt], 0, 0, 0);
            }
        }
    }

    // epilogue: ctx[b, q, h*64+d] bf16  (C-layout: qrow=quad*4+r, d=l16)
    const int b = bh >> 4, h = bh & 15;
#pragma unroll
    for (int r = 0; r < 4; ++r) {
        int q0 = row0 + quad * 4 + r;
        float rl0 = __builtin_amdgcn_rcpf(o1[r]);
        float rl1 = __builtin_amdgcn_rcpf(o1b[r]);
#pragma unroll
        for (int dt = 0; dt < 4; ++dt) {
            Ob[((size_t)(b * TT + q0)) * EE + h * DD + dt * 16 + l16] =
                f2bf(o[dt][r] * rl0);
            Ob[((size_t)(b * TT + q0 + 64)) * EE + h * DD + dt * 16 + l16] =
                f2bf(ob[dt][r] * rl1);
        }
    }
}

// ---------------------------------------------------------------- launch
extern "C" void kernel_launch(void* const* d_in, const int* in_sizes, int n_in,
                              void* d_out, int out_size, void* d_ws, size_t ws_size,
                              hipStream_t stream) {
    const float* hs    = (const float*)d_in[0];
    const float* Wqkv  = (const float*)d_in[1];
    const float* bqkv  = (const float*)d_in[2];
    const float* Wproj = (const float*)d_in[3];
    const float* bproj = (const float*)d_in[4];
    const float* ss    = (const float*)d_in[5];
    // d_in[6] = splat_bias: softmax-invariant (uniform shift of unmasked logits), unused
    float* out = (float*)d_out;

    char* p = (char*)d_ws;
    unsigned short* hsb    = (unsigned short*)p; p += (size_t)MM * EE * 2;      // 16.8 MB (reused as ctx)
    unsigned short* wqkvb  = (unsigned short*)p; p += (size_t)NQKV * EE * 2;    //  6.3 MB
    unsigned short* wprojb = (unsigned short*)p; p += (size_t)EE * EE * 2;      //  2.1 MB
    unsigned short* Qb     = (unsigned short*)p; p += (size_t)BB*HH*TT*DD * 2;  // 16.8 MB
    unsigned short* Kb     = (unsigned short*)p; p += (size_t)BB*HH*TT*DD * 2;  // 16.8 MB
    unsigned short* Vtb    = (unsigned short*)p; p += (size_t)BB*HH*TT*DD * 2;  // 16.8 MB

    cvt_f32_bf16<<<(MM * EE) / 1024, 256, 0, stream>>>(hs, hsb, MM * EE);
    cvt_f32_bf16<<<(NQKV * EE) / 1024, 256, 0, stream>>>(Wqkv, wqkvb, NQKV * EE);
    cvt_f32_bf16<<<(EE * EE) / 1024, 256, 0, stream>>>(Wproj, wprojb, EE * EE);

    gemm_bt<NQKV, EE, 0><<<dim3(NQKV / 128, MM / 128), 256, 0, stream>>>(
        hsb, wqkvb, bqkv, ss, Qb, Kb, Vtb, nullptr);

    flash_attn<<<dim3(1024), 256, 0, stream>>>(Qb, Kb, Vtb, hsb);

    gemm_bt<EE, EE, 1><<<dim3(EE / 128, MM / 128), 256, 0, stream>>>(
        hsb, wprojb, bproj, nullptr, nullptr, nullptr, nullptr, out);
}